// Round 3
// baseline (405.540 us; speedup 1.0000x reference)
//
#include <hip/hip_runtime.h>

// BinaryLinear: y = x @ sign(W)^T + sign(b)
// R6: fat-phase i8 GEMM. R5 post-mortem: per-phase fixed cost ~400cy
// (2 barriers + forced lgkm(0) drain) against only 8 MFMA/phase (326cy)
// -> 37% MfmaUtil. Fix: 2 phases/step x 16 MFMA, 2 barriers/step total
// (vmcnt folded into step-start), compiler-gated lgkm (no manual drain).
//  - ring-4 LDS, depth-3 prefetch, counted vmcnt(8) steady / 8,4,0 tail
//  - T2 XOR chunk swizzle kept (conflicts == 0), T5 setprio kept
// Predicted: gemm 156 -> ~110us, MfmaUtil 37.6 -> ~55%, total -> ~360us.

typedef __attribute__((ext_vector_type(4))) int   i32x4;
typedef __attribute__((ext_vector_type(8))) short short8;
typedef __attribute__((ext_vector_type(4))) float f32x4;

constexpr int M = 8192;
constexpr int N = 4096;
constexpr int K = 4096;

// ---- gemm geometry ----
constexpr int BM = 256, BN = 256, BK = 64;
constexpr int NTILES = K / BK;          // 64
constexpr int TILE_A = BM * BK;         // 16 KiB
constexpr int TILE_B = BN * BK;         // 16 KiB
constexpr int BUFSZ  = TILE_A + TILE_B; // 32 KiB
constexpr int RING   = 4;               // 128 KiB LDS total

__device__ __forceinline__ void load_lds16(const void* g, void* l) {
    __builtin_amdgcn_global_load_lds(
        (const __attribute__((address_space(1))) unsigned int*)g,
        (__attribute__((address_space(3))) unsigned int*)l, 16, 0, 0);
}

// ---------------- fused prep ----------------
// blocks [0, XB): prep_x, one WAVE per row (4 rows/block), no LDS, no sync.
// blocks [XB, XB+WB): prep_w grid-stride, 8 chunks of 32B per thread.
constexpr int XB = M / 4;          // 2048
constexpr int WB = 1024;
constexpr int WCH = N * K / 8;     // uint2 chunks (8 i8 each) = 2M

__global__ __launch_bounds__(256) void prep_fused(
    const float* __restrict__ X, const float* __restrict__ W,
    signed char* __restrict__ Xq, signed char* __restrict__ Wq,
    float* __restrict__ Scale) {
    const int t    = threadIdx.x;
    const int lane = t & 63;
    const int wv   = t >> 6;

    if (blockIdx.x < XB) {
        // ---- prep_x: wave wv handles row 4*blk + wv ----
        const int row = blockIdx.x * 4 + wv;
        const float4* xr = reinterpret_cast<const float4*>(X + (size_t)row * K);
        float4 v[16];
        float mx = 0.f;
#pragma unroll
        for (int i = 0; i < 4; ++i) {
#pragma unroll
            for (int j = 0; j < 4; ++j) {
                float4 f = xr[4 * lane + 256 * i + j];
                v[4 * i + j] = f;
                mx = fmaxf(mx, fmaxf(fmaxf(fabsf(f.x), fabsf(f.y)),
                                     fmaxf(fabsf(f.z), fabsf(f.w))));
            }
        }
#pragma unroll
        for (int off = 32; off > 0; off >>= 1)
            mx = fmaxf(mx, __shfl_down(mx, off));
        mx = __shfl(mx, 0);                    // broadcast wave max
        const float rmax = fmaxf(mx, 1e-20f);
        const float inv  = 127.f / rmax;
        if (lane == 0) Scale[row] = rmax * (1.f / 127.f);

        uint4* out4 = reinterpret_cast<uint4*>(Xq + (size_t)row * K);
#pragma unroll
        for (int i = 0; i < 4; ++i) {
            uint4 o;
            unsigned int* op = &o.x;
#pragma unroll
            for (int j = 0; j < 4; ++j) {
                float4 f = v[4 * i + j];
                int q0 = (int)rintf(f.x * inv);
                int q1 = (int)rintf(f.y * inv);
                int q2 = (int)rintf(f.z * inv);
                int q3 = (int)rintf(f.w * inv);
                op[j] = (q0 & 255) | ((q1 & 255) << 8) |
                        ((q2 & 255) << 16) | ((unsigned)(q3 & 255) << 24);
            }
            out4[lane + 64 * i] = o;
        }
    } else {
        // ---- prep_w: grid-stride, 8 chunks/thread ----
        const float4* W4 = reinterpret_cast<const float4*>(W);
        uint2* O = reinterpret_cast<uint2*>(Wq);
        auto sg = [](float f) -> unsigned int { return (f >= 0.f) ? 1u : 0xFFu; };
        size_t idx = (size_t)(blockIdx.x - XB) * 256 + t;
        const size_t stride = (size_t)WB * 256;
        for (size_t c = idx; c < (size_t)WCH; c += stride) {
            float4 a = W4[c * 2], b = W4[c * 2 + 1];
            uint2 o;
            o.x = sg(a.x) | (sg(a.y) << 8) | (sg(a.z) << 16) | (sg(a.w) << 24);
            o.y = sg(b.x) | (sg(b.y) << 8) | (sg(b.z) << 16) | (sg(b.w) << 24);
            O[c] = o;
        }
    }
}

// ---------------- fat-phase pipelined 256^2 i8 GEMM ----------------
struct GemmCtx {
    const signed char* gA0;
    const signed char* gA1;
    const signed char* gB0;
    const signed char* gB1;
    signed char* lbase;     // wave-uniform stage dest base
    int wm, wn, rl, cq16;
};

// One K-step, 2 fat phases:
//   vmcnt(VMEND) -> s_barrier         (tile t landed; prev-step reads done)
//   reads b0-3,a0-3 | stage A(t+3) | 16 MFMA (m0-3)   [compiler lgkm-gated]
//   reads a4-7      | stage B(t+3) | s_barrier | 16 MFMA (m4-7)
template <bool STAGE, int VMEND>
__device__ __forceinline__ void kstep2(
    const GemmCtx& c, const signed char* smem, int t,
    i32x4 (&b)[4], i32x4 (&acc)[8][4]) {
    const signed char* Ab = smem + (t & (RING - 1)) * BUFSZ;
    const signed char* Bb = Ab + TILE_A;
    signed char* dst = c.lbase + ((t + 3) & (RING - 1)) * BUFSZ;
    const size_t ko = (size_t)(t + 3) * BK;

    // ---- step-start handshake ----
    if constexpr (VMEND >= 0)
        asm volatile("s_waitcnt vmcnt(%0)" :: "i"(VMEND) : "memory");
    __builtin_amdgcn_s_barrier();

    // ---- phase 0 ----
    i32x4 a0[4];
#pragma unroll
    for (int ni = 0; ni < 4; ++ni)
        b[ni] = *reinterpret_cast<const i32x4*>(
            Bb + (c.wn * 64 + ni * 16 + c.rl) * BK + c.cq16);
#pragma unroll
    for (int mi = 0; mi < 4; ++mi)
        a0[mi] = *reinterpret_cast<const i32x4*>(
            Ab + (c.wm * 128 + mi * 16 + c.rl) * BK + c.cq16);
    if constexpr (STAGE) {
        load_lds16(c.gA0 + ko, dst);
        load_lds16(c.gA1 + ko, dst + 8192);
    }
    __builtin_amdgcn_s_setprio(1);
#pragma unroll
    for (int mi = 0; mi < 4; ++mi)
#pragma unroll
        for (int ni = 0; ni < 4; ++ni)
            acc[mi][ni] = __builtin_amdgcn_mfma_i32_16x16x64_i8(
                a0[mi], b[ni], acc[mi][ni], 0, 0, 0);
    __builtin_amdgcn_s_setprio(0);

    // ---- phase 1 ----
    i32x4 a1[4];
#pragma unroll
    for (int mi = 0; mi < 4; ++mi)
        a1[mi] = *reinterpret_cast<const i32x4*>(
            Ab + (c.wm * 128 + (4 + mi) * 16 + c.rl) * BK + c.cq16);
    if constexpr (STAGE) {
        load_lds16(c.gB0 + ko, dst + TILE_A);
        load_lds16(c.gB1 + ko, dst + TILE_A + 8192);
    }
    asm volatile("" ::: "memory");
    __builtin_amdgcn_s_barrier();   // mid-step alignment
    __builtin_amdgcn_s_setprio(1);
#pragma unroll
    for (int mi = 0; mi < 4; ++mi)
#pragma unroll
        for (int ni = 0; ni < 4; ++ni)
            acc[4 + mi][ni] = __builtin_amdgcn_mfma_i32_16x16x64_i8(
                a1[mi], b[ni], acc[4 + mi][ni], 0, 0, 0);
    __builtin_amdgcn_s_setprio(0);
    asm volatile("" ::: "memory");
}

__global__ __launch_bounds__(512, 2) void gemm_i8_p(
    const signed char* __restrict__ Aq, const signed char* __restrict__ Bq,
    const float* __restrict__ Scale, const float* __restrict__ Bias,
    float* __restrict__ OUT) {
    __shared__ signed char smem[RING * BUFSZ];  // 128 KiB

    const int tid  = threadIdx.x;
    const int lane = tid & 63;
    const int w    = tid >> 6;   // 0..7
    GemmCtx c;
    c.wm = w >> 2;               // 0..1 (128-row strip)
    c.wn = w & 3;                // 0..3 (64-col strip)
    c.rl = lane & 15;
    // T2 swizzle: chunk' = (lane>>4) ^ ((rl>>1)&3)
    c.cq16 = (((lane >> 4) ^ ((c.rl >> 1) & 3)) << 4);

    // XCD-aware block swizzle (512 blocks, 512 % 8 == 0 -> bijective)
    const int wg  = blockIdx.x;
    const int lin = (wg & 7) * 64 + (wg >> 3);
    const int n0  = (lin & 15) * BN;
    const int m0  = (lin >> 4) * BM;

    // staging: linear LDS dest (row = tid/4 [+128], chunk = tid&3),
    // global chunk = linear chunk ^ swizzle(row) (same involution as reads)
    const int srow = tid >> 2;                       // 0..127
    const int cg   = ((tid & 3) ^ ((srow >> 1) & 3)) * 16;
    c.gA0 = Aq + (size_t)(m0 + srow)       * K + cg;
    c.gA1 = Aq + (size_t)(m0 + 128 + srow) * K + cg;
    c.gB0 = Bq + (size_t)(n0 + srow)       * K + cg;
    c.gB1 = Bq + (size_t)(n0 + 128 + srow) * K + cg;
    c.lbase = smem + w * 1024;                       // wave-uniform

    auto stage_full = [&](int t) {
        signed char* d = c.lbase + (t & (RING - 1)) * BUFSZ;
        const size_t ko = (size_t)t * BK;
        load_lds16(c.gA0 + ko, d);
        load_lds16(c.gA1 + ko, d + 8192);
        load_lds16(c.gB0 + ko, d + TILE_A);
        load_lds16(c.gB1 + ko, d + TILE_A + 8192);
    };

    i32x4 acc[8][4];
#pragma unroll
    for (int mi = 0; mi < 8; ++mi)
#pragma unroll
        for (int ni = 0; ni < 4; ++ni)
            acc[mi][ni] = (i32x4){0, 0, 0, 0};
    i32x4 b[4];

    // prologue: 3 tiles in flight (12 loads outstanding)
    stage_full(0); stage_full(1); stage_full(2);

    // steady: stage(t+3) during step t; start-of-step vmcnt(8) retires tile t.
    int t = 0;
    for (; t < NTILES - 3; ++t)                      // t = 0..60
        kstep2<true, 8>(c, smem, t, b, acc);
    kstep2<false, 8>(c, smem, t, b, acc); ++t;       // t=61 (outstanding 61,62,63)
    kstep2<false, 4>(c, smem, t, b, acc); ++t;       // t=62
    kstep2<false, 0>(c, smem, t, b, acc);            // t=63

    // epilogue: C/D layout col=lane&15, row=(lane>>4)*4+reg
#pragma unroll
    for (int ni = 0; ni < 4; ++ni) {
        const int gcol = n0 + c.wn * 64 + ni * 16 + c.rl;
        const float sb = (Bias[gcol] >= 0.f) ? 1.f : -1.f;
#pragma unroll
        for (int mi = 0; mi < 8; ++mi) {
            const int growb = m0 + c.wm * 128 + mi * 16 + (lane >> 4) * 4;
            const float4 sc = *reinterpret_cast<const float4*>(&Scale[growb]);
            OUT[(size_t)(growb + 0) * N + gcol] = (float)acc[mi][ni][0] * sc.x + sb;
            OUT[(size_t)(growb + 1) * N + gcol] = (float)acc[mi][ni][1] * sc.y + sb;
            OUT[(size_t)(growb + 2) * N + gcol] = (float)acc[mi][ni][2] * sc.z + sb;
            OUT[(size_t)(growb + 3) * N + gcol] = (float)acc[mi][ni][3] * sc.w + sb;
        }
    }
}

// ---------------- fallback (R1 kernel): used only if ws_size is too small ----
constexpr int MT   = 128;
constexpr int NTF  = 128;
constexpr int LDSS = 40;
constexpr int KTB  = 32;
__device__ __forceinline__ unsigned short f2b(float f) {
    unsigned int u = __builtin_bit_cast(unsigned int, f);
    u += 0x7FFFu + ((u >> 16) & 1u);
    return (unsigned short)(u >> 16);
}
__global__ __launch_bounds__(256) void binlin_fallback(
    const float* __restrict__ X, const float* __restrict__ W,
    const float* __restrict__ B, float* __restrict__ OUT) {
    __shared__ unsigned short As[MT][LDSS];
    __shared__ unsigned short Bs[NTF][LDSS];
    const int tid  = threadIdx.x;
    const int lane = tid & 63;
    const int wave = tid >> 6;
    const int wm   = wave >> 1;
    const int wn   = wave & 1;
    const int m0 = blockIdx.y * MT;
    const int n0 = blockIdx.x * NTF;
    const int rl = lane & 15;
    const int kq = (lane >> 4) * 8;
    f32x4 acc[4][4];
#pragma unroll
    for (int mi = 0; mi < 4; ++mi)
#pragma unroll
        for (int ni = 0; ni < 4; ++ni)
            acc[mi][ni] = (f32x4){0.f, 0.f, 0.f, 0.f};
    for (int k0 = 0; k0 < K; k0 += KTB) {
#pragma unroll
        for (int it = 0; it < 4; ++it) {
            int g = tid + it * 256, row = g >> 3, c4 = (g & 7) << 2;
            float4 v = *reinterpret_cast<const float4*>(&X[(size_t)(m0 + row) * K + k0 + c4]);
            ushort4 h;
            h.x = f2b(v.x); h.y = f2b(v.y); h.z = f2b(v.z); h.w = f2b(v.w);
            *reinterpret_cast<ushort4*>(&As[row][c4]) = h;
        }
#pragma unroll
        for (int it = 0; it < 4; ++it) {
            int g = tid + it * 256, row = g >> 3, c4 = (g & 7) << 2;
            float4 v = *reinterpret_cast<const float4*>(&W[(size_t)(n0 + row) * K + k0 + c4]);
            ushort4 h;
            h.x = (v.x >= 0.f) ? 0x3F80u : 0xBF80u;
            h.y = (v.y >= 0.f) ? 0x3F80u : 0xBF80u;
            h.z = (v.z >= 0.f) ? 0x3F80u : 0xBF80u;
            h.w = (v.w >= 0.f) ? 0x3F80u : 0xBF80u;
            *reinterpret_cast<ushort4*>(&Bs[row][c4]) = h;
        }
        __syncthreads();
        short8 a[4], b[4];
#pragma unroll
        for (int mi = 0; mi < 4; ++mi)
            a[mi] = *reinterpret_cast<const short8*>(&As[wm * 64 + mi * 16 + rl][kq]);
#pragma unroll
        for (int ni = 0; ni < 4; ++ni)
            b[ni] = *reinterpret_cast<const short8*>(&Bs[wn * 64 + ni * 16 + rl][kq]);
#pragma unroll
        for (int mi = 0; mi < 4; ++mi)
#pragma unroll
            for (int ni = 0; ni < 4; ++ni)
                acc[mi][ni] = __builtin_amdgcn_mfma_f32_16x16x32_bf16(
                    a[mi], b[ni], acc[mi][ni], 0, 0, 0);
        __syncthreads();
    }
#pragma unroll
    for (int ni = 0; ni < 4; ++ni) {
        int gcol = n0 + wn * 64 + ni * 16 + rl;
        float sb = (B[gcol] >= 0.f) ? 1.f : -1.f;
#pragma unroll
        for (int mi = 0; mi < 4; ++mi) {
            int growb = m0 + wm * 64 + mi * 16 + (lane >> 4) * 4;
#pragma unroll
            for (int r = 0; r < 4; ++r)
                OUT[(size_t)(growb + r) * N + gcol] = acc[mi][ni][r] + sb;
        }
    }
}

extern "C" void kernel_launch(void* const* d_in, const int* in_sizes, int n_in,
                              void* d_out, int out_size, void* d_ws, size_t ws_size,
                              hipStream_t stream) {
    const float* x  = (const float*)d_in[0];
    const float* w  = (const float*)d_in[1];
    const float* b  = (const float*)d_in[2];
    float* out      = (float*)d_out;

    // ws layout: Xq [M*K i8] | Wq [N*K i8] | Scale [M f32]
    const size_t need = (size_t)M * K + (size_t)N * K + (size_t)M * sizeof(float);
    if (ws_size >= need) {
        signed char* Xq = (signed char*)d_ws;
        signed char* Wq = Xq + (size_t)M * K;
        float* Scale    = (float*)(Wq + (size_t)N * K);

        prep_fused<<<dim3(XB + WB), dim3(256), 0, stream>>>(x, w, Xq, Wq, Scale);
        gemm_i8_p<<<dim3((M / BM) * (N / BN)), dim3(512), 0, stream>>>(
            Xq, Wq, Scale, b, out);
    } else {
        dim3 grid(N / NTF, M / MT);
        binlin_fallback<<<grid, dim3(256), 0, stream>>>(x, w, b, out);
    }
}